// Round 1
// baseline (692.826 us; speedup 1.0000x reference)
//
#include <hip/hip_runtime.h>
#include <stdint.h>

#define N_SRCN 50000
#define N_DSTN 50000
#define NE     800000
#define D_INF  64
#define HIDN   256
#define NEG    0.2f

typedef __attribute__((ext_vector_type(8)))  short short8;
typedef __attribute__((ext_vector_type(16))) float float16v;

__device__ __forceinline__ float bf2f(unsigned short u){
    union { unsigned u32; float f; } c; c.u32 = ((unsigned)u) << 16; return c.f;
}
__device__ __forceinline__ unsigned short f2bf(float f){
    union { float f; unsigned u; } c; c.f = f;
    unsigned r = c.u + 0x7fffu + ((c.u >> 16) & 1u);
    return (unsigned short)(r >> 16);
}
__device__ __forceinline__ float4 ld4b(const unsigned short* p){
    uint2 u = *reinterpret_cast<const uint2*>(p);
    float4 r;
    r.x = bf2f((unsigned short)(u.x & 0xffff));
    r.y = bf2f((unsigned short)(u.x >> 16));
    r.z = bf2f((unsigned short)(u.y & 0xffff));
    r.w = bf2f((unsigned short)(u.y >> 16));
    return r;
}

// ---------------- pack weights: W_src/W_dst/W_res transposed->bf16, W_ih/W_hh ->bf16
__global__ void pack_kernel(const float* __restrict__ Wsrc, const float* __restrict__ Wdst,
                            const float* __restrict__ Wres, const float* __restrict__ Wih,
                            const float* __restrict__ Whh,
                            unsigned short* __restrict__ Wt,   // 3 * 256*64  [n][k]
                            unsigned short* __restrict__ WihB, // 768*256
                            unsigned short* __restrict__ WhhB){
    int i = blockIdx.x * 256 + threadIdx.x;
    if (i < 3 * 16384){
        int which = i / 16384, j = i % 16384;
        int n = j >> 6, k = j & 63;
        const float* W = (which == 0) ? Wsrc : (which == 1 ? Wdst : Wres);
        Wt[i] = f2bf(W[k * 256 + n]);
    } else {
        int i2 = i - 3 * 16384;
        if (i2 < 196608) WihB[i2] = f2bf(Wih[i2]);
        else { int i3 = i2 - 196608; if (i3 < 196608) WhhB[i3] = f2bf(Whh[i3]); }
    }
}

// ---------------- projection GEMM: out[m][c] = sum_k A[m][k]*W[k][c] + b[c], K=64, out bf16
// Wt is [256][64] bf16 (n-major).  block: 4 waves 2x2 -> 64 rows x 64 cols tile.
__global__ __launch_bounds__(256) void proj_kernel(
        const float* __restrict__ A, const unsigned short* __restrict__ Wt,
        const float* __restrict__ bias, unsigned short* __restrict__ out){
    __shared__ unsigned short As[64 * 72];
    int tid = threadIdx.x;
    int m0 = blockIdx.y * 64;
    int c0 = blockIdx.x * 64;
    #pragma unroll
    for (int i = 0; i < 4; ++i){
        int ci = tid + i * 256;          // 1024 float4 chunks
        int row = ci >> 4;               // 16 chunks / row
        int k4 = (ci & 15) << 2;
        int gr = m0 + row; if (gr >= N_SRCN) gr = N_SRCN - 1;
        float4 v = *reinterpret_cast<const float4*>(A + gr * 64 + k4);
        unsigned short* d = As + row * 72 + k4;
        d[0] = f2bf(v.x); d[1] = f2bf(v.y); d[2] = f2bf(v.z); d[3] = f2bf(v.w);
    }
    __syncthreads();
    int lane = tid & 63, w = tid >> 6;
    int msub = (w & 1) * 32, csub = (w >> 1) * 32;
    int l31 = lane & 31, half = lane >> 5;
    float16v acc = {0,0,0,0,0,0,0,0,0,0,0,0,0,0,0,0};
    const unsigned short* bp = Wt + (c0 + csub + l31) * 64 + half * 8;
    const unsigned short* ap = As + (msub + l31) * 72 + half * 8;
    #pragma unroll
    for (int ks = 0; ks < 4; ++ks){
        short8 a = *reinterpret_cast<const short8*>(ap + ks * 16);
        short8 b = *reinterpret_cast<const short8*>(bp + ks * 16);
        acc = __builtin_amdgcn_mfma_f32_32x32x16_bf16(a, b, acc, 0, 0, 0);
    }
    float bv = bias[c0 + csub + l31];
    #pragma unroll
    for (int r = 0; r < 16; ++r){
        int row = (r & 3) + 8 * (r >> 2) + 4 * half + msub;
        int m = m0 + row;
        if (m < N_SRCN) out[m * HIDN + c0 + csub + l31] = f2bf(acc[r] + bv);
    }
}

// ---------------- edge CSR build
__global__ void degree_kernel(const int* __restrict__ dst, int* __restrict__ deg){
    int i = blockIdx.x * 256 + threadIdx.x;
    if (i < NE) atomicAdd(&deg[dst[i]], 1);
}

__global__ void scan_kernel(const int* __restrict__ deg, int* __restrict__ ptr,
                            int* __restrict__ cursor){
    __shared__ int s[1024];
    int t = threadIdx.x;
    int lo = t * 49, hi = min(N_DSTN, lo + 49);
    int sum = 0;
    for (int i = lo; i < hi; ++i) sum += deg[i];
    s[t] = sum;
    __syncthreads();
    for (int off = 1; off < 1024; off <<= 1){
        int v = (t >= off) ? s[t - off] : 0;
        __syncthreads();
        s[t] += v;
        __syncthreads();
    }
    int run = s[t] - sum;   // exclusive prefix
    for (int i = lo; i < hi; ++i){ ptr[i] = run; cursor[i] = run; run += deg[i]; }
}

__global__ void scatter_kernel(const int* __restrict__ src, const int* __restrict__ dst,
                               int* __restrict__ cursor, int* __restrict__ csr){
    int i = blockIdx.x * 256 + threadIdx.x;
    if (i < NE){
        int d = dst[i];
        int pos = atomicAdd(&cursor[d], 1);
        csr[pos] = src[i];
    }
}

// ---------------- per-dst online-softmax aggregation: one wave per dst node
__global__ __launch_bounds__(256) void aggregate_kernel(
        const unsigned short* __restrict__ fs, const unsigned short* __restrict__ fd,
        const unsigned short* __restrict__ res, const float* __restrict__ attn,
        const int* __restrict__ ptr, const int* __restrict__ deg,
        const int* __restrict__ csr, unsigned short* __restrict__ x){
    int wv = threadIdx.x >> 6;
    int d = blockIdx.x * 4 + wv;
    if (d >= N_DSTN) return;
    int lane = threadIdx.x & 63;
    int c4 = lane * 4;
    float4 fdv = ld4b(fd + d * 256 + c4);
    float4 at = *reinterpret_cast<const float4*>(attn + (lane >> 4) * 64 + (lane & 15) * 4);
    int p = ptr[d], dg = deg[d];
    float m = -INFINITY, l = 0.f;
    float4 acc = make_float4(0.f, 0.f, 0.f, 0.f);
    for (int base = 0; base < dg; base += 64){
        int cnt = min(64, dg - base);
        int sreg = (lane < cnt) ? csr[p + base + lane] : 0;
        int s0 = __shfl(sreg, 0);
        float4 cur = ld4b(fs + s0 * 256 + c4);
        for (int j = 0; j < cnt; ++j){
            float4 nxt = cur;
            if (j + 1 < cnt){
                int s1 = __shfl(sreg, j + 1);
                nxt = ld4b(fs + s1 * 256 + c4);
            }
            float ex = cur.x + fdv.x; ex = ex > 0.f ? ex : NEG * ex;
            float ey = cur.y + fdv.y; ey = ey > 0.f ? ey : NEG * ey;
            float ez = cur.z + fdv.z; ez = ez > 0.f ? ez : NEG * ez;
            float ew = cur.w + fdv.w; ew = ew > 0.f ? ew : NEG * ew;
            float part = ex * at.x + ey * at.y + ez * at.z + ew * at.w;
            part += __shfl_xor(part, 1);
            part += __shfl_xor(part, 2);
            part += __shfl_xor(part, 4);
            part += __shfl_xor(part, 8);
            float mn = fmaxf(m, part);
            float scl = __expf(m - mn);
            float wgt = __expf(part - mn);
            l = l * scl + wgt;
            acc.x = acc.x * scl + wgt * cur.x;
            acc.y = acc.y * scl + wgt * cur.y;
            acc.z = acc.z * scl + wgt * cur.z;
            acc.w = acc.w * scl + wgt * cur.w;
            m = mn;
            cur = nxt;
        }
    }
    float inv = (l > 0.f) ? 1.f / l : 0.f;
    float4 rv = ld4b(res + d * 256 + c4);
    float xx = fmaxf(acc.x * inv + rv.x, 0.f);
    float xy = fmaxf(acc.y * inv + rv.y, 0.f);
    float xz = fmaxf(acc.z * inv + rv.z, 0.f);
    float xw = fmaxf(acc.w * inv + rv.w, 0.f);
    uint2 o;
    o.x = (unsigned)f2bf(xx) | ((unsigned)f2bf(xy) << 16);
    o.y = (unsigned)f2bf(xz) | ((unsigned)f2bf(xw) << 16);
    *reinterpret_cast<uint2*>(x + d * 256 + c4) = o;
}

// ---------------- fused GRU: h = (1-z)*n + z*h0, 6 MFMA acc tiles per wave
__global__ __launch_bounds__(256) void gru_kernel(
        const unsigned short* __restrict__ Xb, const float* __restrict__ H0,
        const unsigned short* __restrict__ Wih, const unsigned short* __restrict__ Whh,
        const float* __restrict__ bih, const float* __restrict__ bhh,
        float* __restrict__ outH){
    __shared__ unsigned short Xs[64 * 136];
    __shared__ unsigned short Hs[64 * 136];
    int tid = threadIdx.x;
    int m0 = blockIdx.y * 64;
    int c0 = blockIdx.x * 64;
    int lane = tid & 63, w = tid >> 6;
    int msub = (w & 1) * 32, csub = (w >> 1) * 32;
    int l31 = lane & 31, half = lane >> 5;
    int cg = c0 + csub + l31;          // gate column in [0,256)
    const unsigned short* pi = Wih + cg * 256 + half * 8;
    const unsigned short* ph = Whh + cg * 256 + half * 8;
    float16v ai0 = {0,0,0,0,0,0,0,0,0,0,0,0,0,0,0,0};
    float16v ai1 = ai0, ai2 = ai0, ah0 = ai0, ah1 = ai0, ah2 = ai0;
    for (int kc = 0; kc < 256; kc += 128){
        __syncthreads();
        #pragma unroll
        for (int i = 0; i < 4; ++i){       // X tile: 1024 x 16B chunks (bf16 copy)
            int ci = tid + i * 256;
            int row = ci >> 4;
            int k8 = (ci & 15) << 3;
            int gr = m0 + row; if (gr >= N_DSTN) gr = N_DSTN - 1;
            *reinterpret_cast<uint4*>(Xs + row * 136 + k8) =
                *reinterpret_cast<const uint4*>(Xb + gr * 256 + kc + k8);
        }
        #pragma unroll
        for (int i = 0; i < 8; ++i){       // H0 tile: f32 -> bf16
            int ci = tid + i * 256;
            int row = ci >> 5;
            int k4 = (ci & 31) << 2;
            int gr = m0 + row; if (gr >= N_DSTN) gr = N_DSTN - 1;
            float4 v = *reinterpret_cast<const float4*>(H0 + gr * 256 + kc + k4);
            unsigned short* dp = Hs + row * 136 + k4;
            dp[0] = f2bf(v.x); dp[1] = f2bf(v.y); dp[2] = f2bf(v.z); dp[3] = f2bf(v.w);
        }
        __syncthreads();
        const unsigned short* ax = Xs + (msub + l31) * 136 + half * 8;
        const unsigned short* ah = Hs + (msub + l31) * 136 + half * 8;
        #pragma unroll
        for (int ks = 0; ks < 8; ++ks){
            int k0 = kc + ks * 16;
            short8 a_x = *reinterpret_cast<const short8*>(ax + ks * 16);
            short8 a_h = *reinterpret_cast<const short8*>(ah + ks * 16);
            short8 b0 = *reinterpret_cast<const short8*>(pi + k0);
            short8 b1 = *reinterpret_cast<const short8*>(pi + 65536 + k0);
            short8 b2 = *reinterpret_cast<const short8*>(pi + 131072 + k0);
            short8 c0v = *reinterpret_cast<const short8*>(ph + k0);
            short8 c1v = *reinterpret_cast<const short8*>(ph + 65536 + k0);
            short8 c2v = *reinterpret_cast<const short8*>(ph + 131072 + k0);
            ai0 = __builtin_amdgcn_mfma_f32_32x32x16_bf16(a_x, b0, ai0, 0, 0, 0);
            ai1 = __builtin_amdgcn_mfma_f32_32x32x16_bf16(a_x, b1, ai1, 0, 0, 0);
            ai2 = __builtin_amdgcn_mfma_f32_32x32x16_bf16(a_x, b2, ai2, 0, 0, 0);
            ah0 = __builtin_amdgcn_mfma_f32_32x32x16_bf16(a_h, c0v, ah0, 0, 0, 0);
            ah1 = __builtin_amdgcn_mfma_f32_32x32x16_bf16(a_h, c1v, ah1, 0, 0, 0);
            ah2 = __builtin_amdgcn_mfma_f32_32x32x16_bf16(a_h, c2v, ah2, 0, 0, 0);
        }
    }
    float bi0 = bih[cg], bi1 = bih[256 + cg], bi2 = bih[512 + cg];
    float bh0 = bhh[cg], bh1 = bhh[256 + cg], bh2 = bhh[512 + cg];
    #pragma unroll
    for (int r = 0; r < 16; ++r){
        int row = (r & 3) + 8 * (r >> 2) + 4 * half + msub;
        int m = m0 + row;
        if (m < N_DSTN){
            float h0v = H0[m * 256 + cg];
            float rr = 1.f / (1.f + __expf(-(ai0[r] + bi0 + ah0[r] + bh0)));
            float zz = 1.f / (1.f + __expf(-(ai1[r] + bi1 + ah1[r] + bh1)));
            float nx = ai2[r] + bi2 + rr * (ah2[r] + bh2);
            float tm = __expf(-2.f * fabsf(nx));
            float nn = (1.f - tm) / (1.f + tm);
            nn = (nx >= 0.f) ? nn : -nn;
            outH[m * 256 + cg] = (1.f - zz) * nn + zz * h0v;
        }
    }
}

// ---------------- logits = h @ W_out + b_out
__global__ __launch_bounds__(256) void logits_kernel(
        const float* __restrict__ H, const float* __restrict__ Wout,
        const float* __restrict__ bout, float* __restrict__ outL){
    __shared__ float Hl[16 * 257];
    __shared__ float Wl[256 * 16];
    int tid = threadIdx.x;
    int m0 = blockIdx.x * 16;
    #pragma unroll
    for (int i = 0; i < 4; ++i){
        int ci = tid + i * 256;          // 1024 float4 chunks: 16 rows x 64
        int row = ci >> 6;
        int k4 = (ci & 63) << 2;
        int gr = m0 + row; if (gr >= N_DSTN) gr = N_DSTN - 1;
        float4 v = *reinterpret_cast<const float4*>(H + gr * 256 + k4);
        float* dp = Hl + row * 257 + k4;
        dp[0] = v.x; dp[1] = v.y; dp[2] = v.z; dp[3] = v.w;
    }
    #pragma unroll
    for (int i = 0; i < 16; ++i) Wl[tid + i * 256] = Wout[tid + i * 256];
    __syncthreads();
    int row = tid >> 4, j = tid & 15;
    float acc = bout[j];
    const float* hr = Hl + row * 257;
    #pragma unroll 8
    for (int c = 0; c < 256; ++c) acc += hr[c] * Wl[c * 16 + j];
    int m = m0 + row;
    if (m < N_DSTN) outL[m * 16 + j] = acc;
}

extern "C" void kernel_launch(void* const* d_in, const int* in_sizes, int n_in,
                              void* d_out, int out_size, void* d_ws, size_t ws_size,
                              hipStream_t stream){
    const float* feat_gt = (const float*)d_in[0];
    const float* feat_ag = (const float*)d_in[1];
    const float* h0      = (const float*)d_in[2];
    const int*   e_dst   = (const int*)d_in[4];
    const float* W_src   = (const float*)d_in[5];
    const float* b_src   = (const float*)d_in[6];
    const float* W_dst   = (const float*)d_in[7];
    const float* b_dst   = (const float*)d_in[8];
    const float* attn    = (const float*)d_in[9];
    const float* W_res   = (const float*)d_in[10];
    const float* b_res   = (const float*)d_in[11];
    const float* W_ih    = (const float*)d_in[12];
    const float* W_hh    = (const float*)d_in[13];
    const float* b_ih    = (const float*)d_in[14];
    const float* b_hh    = (const float*)d_in[15];
    const float* W_out   = (const float*)d_in[16];
    const float* b_out   = (const float*)d_in[17];
    const int*   e_src   = (const int*)d_in[3];

    float* outL = (float*)d_out;
    float* outH = outL + (size_t)N_DSTN * 16;

    char* ws = (char*)d_ws;
    size_t off = 0;
    auto alloc = [&](size_t bytes) -> void* {
        void* p = ws + off; off = (off + bytes + 255) & ~(size_t)255; return p;
    };
    unsigned short* fs   = (unsigned short*)alloc((size_t)N_SRCN * 256 * 2);
    unsigned short* fd   = (unsigned short*)alloc((size_t)N_DSTN * 256 * 2);
    unsigned short* res  = (unsigned short*)alloc((size_t)N_DSTN * 256 * 2);
    unsigned short* xb   = (unsigned short*)alloc((size_t)N_DSTN * 256 * 2);
    unsigned short* Wt   = (unsigned short*)alloc(3 * 16384 * 2);
    unsigned short* WihB = (unsigned short*)alloc(196608 * 2);
    unsigned short* WhhB = (unsigned short*)alloc(196608 * 2);
    int* deg    = (int*)alloc(N_DSTN * 4);
    int* ptr    = (int*)alloc(N_DSTN * 4);
    int* cursor = (int*)alloc(N_DSTN * 4);
    int* csr    = (int*)alloc((size_t)NE * 4);

    hipMemsetAsync(deg, 0, N_DSTN * 4, stream);
    pack_kernel<<<1728, 256, 0, stream>>>(W_src, W_dst, W_res, W_ih, W_hh, Wt, WihB, WhhB);

    dim3 pg(4, 782);
    proj_kernel<<<pg, 256, 0, stream>>>(feat_gt, Wt, b_src, fs);
    proj_kernel<<<pg, 256, 0, stream>>>(feat_ag, Wt + 16384, b_dst, fd);
    proj_kernel<<<pg, 256, 0, stream>>>(feat_ag, Wt + 32768, b_res, res);

    degree_kernel<<<3125, 256, 0, stream>>>(e_dst, deg);
    scan_kernel<<<1, 1024, 0, stream>>>(deg, ptr, cursor);
    scatter_kernel<<<3125, 256, 0, stream>>>(e_src, e_dst, cursor, csr);
    aggregate_kernel<<<12500, 256, 0, stream>>>(fs, fd, res, attn, ptr, deg, csr, xb);

    gru_kernel<<<dim3(4, 782), 256, 0, stream>>>(xb, h0, WihB, WhhB, b_ih, b_hh, outH);
    logits_kernel<<<3125, 256, 0, stream>>>(outH, W_out, b_out, outL);
}

// Round 2
// 601.274 us; speedup vs baseline: 1.1523x; 1.1523x over previous
//
#include <hip/hip_runtime.h>
#include <stdint.h>

#define N_SRCN 50000
#define N_DSTN 50000
#define NE     800000
#define HIDN   256
#define NEG    0.2f

typedef __attribute__((ext_vector_type(8)))  short short8;
typedef __attribute__((ext_vector_type(16))) float float16v;

__device__ __forceinline__ float bf2f(unsigned short u){
    union { unsigned u32; float f; } c; c.u32 = ((unsigned)u) << 16; return c.f;
}
__device__ __forceinline__ unsigned short f2bf(float f){
    union { float f; unsigned u; } c; c.f = f;
    unsigned r = c.u + 0x7fffu + ((c.u >> 16) & 1u);
    return (unsigned short)(r >> 16);
}
__device__ __forceinline__ float4 ld4b(const unsigned short* p){
    uint2 u = *reinterpret_cast<const uint2*>(p);
    float4 r;
    r.x = bf2f((unsigned short)(u.x & 0xffff));
    r.y = bf2f((unsigned short)(u.x >> 16));
    r.z = bf2f((unsigned short)(u.y & 0xffff));
    r.w = bf2f((unsigned short)(u.y >> 16));
    return r;
}

// ---- pack weights into MFMA-fragment-contiguous bf16 layouts --------------
// Wt2: 3 proj mats, [which][cb(8)][kk(4)][lane(64)][8]  (49152 elems)
// Wf : GRU,        [g(3)][cb(8)][kk(32)][lane(64)][8]   (393216 elems), K=512 = [Wih|Whh]
__global__ void pack_kernel(const float* __restrict__ Wsrc, const float* __restrict__ Wdst,
                            const float* __restrict__ Wres, const float* __restrict__ Wih,
                            const float* __restrict__ Whh,
                            unsigned short* __restrict__ Wt2,
                            unsigned short* __restrict__ Wf){
    int i = blockIdx.x * 256 + threadIdx.x;
    if (i < 49152){
        int o = i;
        int j = o & 7, lane = (o >> 3) & 63, kk = (o >> 9) & 3, cb = (o >> 11) & 7, which = o >> 14;
        int c = cb * 32 + (lane & 31);
        int k = kk * 16 + (lane >> 5) * 8 + j;
        const float* W = (which == 0) ? Wsrc : (which == 1 ? Wdst : Wres);
        Wt2[i] = f2bf(W[k * 256 + c]);
    } else if (i < 49152 + 393216){
        int o = i - 49152;
        int j = o & 7, lane = (o >> 3) & 63, kk = (o >> 9) & 31, cb = (o >> 14) & 7, g = o >> 17;
        int c = cb * 32 + (lane & 31);
        int k = kk * 16 + (lane >> 5) * 8 + j;
        float v = (k < 256) ? Wih[(g * 256 + c) * 256 + k]
                            : Whh[(g * 256 + c) * 256 + (k - 256)];
        Wf[o] = f2bf(v);
    }
}

// ---- h0 f32 -> bf16 -------------------------------------------------------
__global__ void convh_kernel(const float* __restrict__ h, unsigned short* __restrict__ hb){
    int i = blockIdx.x * 256 + threadIdx.x;      // 3,200,000 float4 chunks
    if (i < N_DSTN * 64){
        float4 v = reinterpret_cast<const float4*>(h)[i];
        uint2 o;
        o.x = (unsigned)f2bf(v.x) | ((unsigned)f2bf(v.y) << 16);
        o.y = (unsigned)f2bf(v.z) | ((unsigned)f2bf(v.w) << 16);
        reinterpret_cast<uint2*>(hb)[i] = o;
    }
}

// ---- projection GEMM (K=64), coalesced B fragments ------------------------
__global__ __launch_bounds__(256) void proj_kernel(
        const float* __restrict__ A, const unsigned short* __restrict__ Wt2,
        const float* __restrict__ bias, unsigned short* __restrict__ out){
    __shared__ unsigned short As[64 * 72];
    int tid = threadIdx.x;
    int m0 = blockIdx.y * 64;
    #pragma unroll
    for (int i = 0; i < 4; ++i){
        int ci = tid + i * 256;
        int row = ci >> 4;
        int k4 = (ci & 15) << 2;
        int gr = m0 + row; if (gr >= N_SRCN) gr = N_SRCN - 1;
        float4 v = *reinterpret_cast<const float4*>(A + (size_t)gr * 64 + k4);
        unsigned short* dp = As + row * 72 + k4;
        dp[0] = f2bf(v.x); dp[1] = f2bf(v.y); dp[2] = f2bf(v.z); dp[3] = f2bf(v.w);
    }
    __syncthreads();
    int lane = tid & 63, w = tid >> 6;
    int l31 = lane & 31, half = lane >> 5;
    int msub = (w & 1) * 32;
    int cbw = blockIdx.x * 2 + (w >> 1);         // 0..7
    const unsigned short* bb = Wt2 + cbw * 2048 + lane * 8;
    const unsigned short* ap = As + (msub + l31) * 72 + half * 8;
    float16v acc = {0,0,0,0,0,0,0,0,0,0,0,0,0,0,0,0};
    #pragma unroll
    for (int ks = 0; ks < 4; ++ks){
        short8 a = *reinterpret_cast<const short8*>(ap + ks * 16);
        short8 b = *reinterpret_cast<const short8*>(bb + ks * 512);
        acc = __builtin_amdgcn_mfma_f32_32x32x16_bf16(a, b, acc, 0, 0, 0);
    }
    int cg = cbw * 32 + l31;
    float bv = bias[cg];
    #pragma unroll
    for (int r = 0; r < 16; ++r){
        int row = (r & 3) + 8 * (r >> 2) + 4 * half + msub;
        int m = m0 + row;
        if (m < N_SRCN) out[(size_t)m * HIDN + cg] = f2bf(acc[r] + bv);
    }
}

// ---- edge CSR build -------------------------------------------------------
__global__ void degree_kernel(const int* __restrict__ dst, int* __restrict__ deg){
    int i = blockIdx.x * 256 + threadIdx.x;
    if (i < NE) atomicAdd(&deg[dst[i]], 1);
}

__global__ void scan_kernel(const int* __restrict__ deg, int* __restrict__ ptr,
                            int* __restrict__ cursor){
    __shared__ int s[1024];
    int t = threadIdx.x;
    int lo = t * 49, hi = min(N_DSTN, lo + 49);
    int sum = 0;
    for (int i = lo; i < hi; ++i) sum += deg[i];
    s[t] = sum;
    __syncthreads();
    for (int off = 1; off < 1024; off <<= 1){
        int v = (t >= off) ? s[t - off] : 0;
        __syncthreads();
        s[t] += v;
        __syncthreads();
    }
    int run = s[t] - sum;
    for (int i = lo; i < hi; ++i){ ptr[i] = run; cursor[i] = run; run += deg[i]; }
}

__global__ void scatter_kernel(const int* __restrict__ src, const int* __restrict__ dst,
                               int* __restrict__ cursor, int* __restrict__ csr){
    int i = blockIdx.x * 256 + threadIdx.x;
    if (i < NE){
        int d = dst[i];
        int pos = atomicAdd(&cursor[d], 1);
        csr[pos] = src[i];
    }
}

// ---- per-dst online-softmax aggregation (one wave per dst) ----------------
__global__ __launch_bounds__(256) void aggregate_kernel(
        const unsigned short* __restrict__ fs, const unsigned short* __restrict__ fd,
        const unsigned short* __restrict__ res, const float* __restrict__ attn,
        const int* __restrict__ ptr, const int* __restrict__ deg,
        const int* __restrict__ csr, unsigned short* __restrict__ x){
    int wv = threadIdx.x >> 6;
    int d = blockIdx.x * 4 + wv;
    if (d >= N_DSTN) return;
    int lane = threadIdx.x & 63;
    int c4 = lane * 4;
    float4 fdv = ld4b(fd + (size_t)d * 256 + c4);
    float4 at = *reinterpret_cast<const float4*>(attn + (lane >> 4) * 64 + (lane & 15) * 4);
    int p = ptr[d], dg = deg[d];
    float m = -INFINITY, l = 0.f;
    float4 acc = make_float4(0.f, 0.f, 0.f, 0.f);
    for (int base = 0; base < dg; base += 64){
        int cnt = min(64, dg - base);
        int sreg = (lane < cnt) ? csr[p + base + lane] : 0;
        int s0 = __shfl(sreg, 0);
        float4 cur = ld4b(fs + (size_t)s0 * 256 + c4);
        for (int j = 0; j < cnt; ++j){
            float4 nxt = cur;
            if (j + 1 < cnt){
                int s1 = __shfl(sreg, j + 1);
                nxt = ld4b(fs + (size_t)s1 * 256 + c4);
            }
            float ex = cur.x + fdv.x; ex = ex > 0.f ? ex : NEG * ex;
            float ey = cur.y + fdv.y; ey = ey > 0.f ? ey : NEG * ey;
            float ez = cur.z + fdv.z; ez = ez > 0.f ? ez : NEG * ez;
            float ew = cur.w + fdv.w; ew = ew > 0.f ? ew : NEG * ew;
            float part = ex * at.x + ey * at.y + ez * at.z + ew * at.w;
            part += __shfl_xor(part, 1);
            part += __shfl_xor(part, 2);
            part += __shfl_xor(part, 4);
            part += __shfl_xor(part, 8);
            float mn = fmaxf(m, part);
            float scl = __expf(m - mn);
            float wgt = __expf(part - mn);
            l = l * scl + wgt;
            acc.x = acc.x * scl + wgt * cur.x;
            acc.y = acc.y * scl + wgt * cur.y;
            acc.z = acc.z * scl + wgt * cur.z;
            acc.w = acc.w * scl + wgt * cur.w;
            m = mn;
            cur = nxt;
        }
    }
    float inv = (l > 0.f) ? 1.f / l : 0.f;
    float4 rv = ld4b(res + (size_t)d * 256 + c4);
    float xx = fmaxf(acc.x * inv + rv.x, 0.f);
    float xy = fmaxf(acc.y * inv + rv.y, 0.f);
    float xz = fmaxf(acc.z * inv + rv.z, 0.f);
    float xw = fmaxf(acc.w * inv + rv.w, 0.f);
    uint2 o;
    o.x = (unsigned)f2bf(xx) | ((unsigned)f2bf(xy) << 16);
    o.y = (unsigned)f2bf(xz) | ((unsigned)f2bf(xw) << 16);
    *reinterpret_cast<uint2*>(x + (size_t)d * 256 + c4) = o;
}

// ---- fused GRU v2: K=512 [X|H] bf16, merged r/z accs, coalesced B ---------
// block: 64 rows x 128 cols; wave: 64 rows (2 msubs) x 32 cols; 8 acc tiles.
__global__ __launch_bounds__(256) void gru_kernel(
        const unsigned short* __restrict__ Xb, const unsigned short* __restrict__ Hb,
        const float* __restrict__ H0, const unsigned short* __restrict__ Wf,
        const float* __restrict__ bih, const float* __restrict__ bhh,
        float* __restrict__ outH){
    __shared__ unsigned short As[64 * 136];
    int tid = threadIdx.x;
    int m0 = blockIdx.y * 64;
    int w = tid >> 6, lane = tid & 63;
    int l31 = lane & 31, half = lane >> 5;
    int cb = blockIdx.x * 4 + w;                 // 0..7
    int cg = cb * 32 + l31;
    const unsigned short* bb = Wf + (size_t)cb * 16384 + lane * 8;
    float16v ar0 = {0,0,0,0,0,0,0,0,0,0,0,0,0,0,0,0};
    float16v ar1 = ar0, az0 = ar0, az1 = ar0, anx0 = ar0, anx1 = ar0, anh0 = ar0, anh1 = ar0;
    #pragma unroll
    for (int kc = 0; kc < 512; kc += 128){
        const unsigned short* srcb = (kc < 256) ? (Xb + kc) : (Hb + (kc - 256));
        __syncthreads();
        #pragma unroll
        for (int i = 0; i < 4; ++i){
            int ci = tid + i * 256;              // 1024 chunks: 64 rows x 16 x 16B
            int row = ci >> 4;
            int k8 = (ci & 15) << 3;
            int gr = m0 + row; if (gr >= N_DSTN) gr = N_DSTN - 1;
            *reinterpret_cast<uint4*>(As + row * 136 + k8) =
                *reinterpret_cast<const uint4*>(srcb + (size_t)gr * 256 + k8);
        }
        __syncthreads();
        const unsigned short* a0p = As + l31 * 136 + half * 8;
        const unsigned short* a1p = As + (l31 + 32) * 136 + half * 8;
        #pragma unroll
        for (int ks = 0; ks < 8; ++ks){
            int kk = (kc >> 4) + ks;             // 0..31
            short8 a0 = *reinterpret_cast<const short8*>(a0p + ks * 16);
            short8 a1 = *reinterpret_cast<const short8*>(a1p + ks * 16);
            short8 br = *reinterpret_cast<const short8*>(bb + (size_t)kk * 512);
            short8 bz = *reinterpret_cast<const short8*>(bb + 131072 + (size_t)kk * 512);
            short8 bn = *reinterpret_cast<const short8*>(bb + 262144 + (size_t)kk * 512);
            ar0 = __builtin_amdgcn_mfma_f32_32x32x16_bf16(a0, br, ar0, 0, 0, 0);
            ar1 = __builtin_amdgcn_mfma_f32_32x32x16_bf16(a1, br, ar1, 0, 0, 0);
            az0 = __builtin_amdgcn_mfma_f32_32x32x16_bf16(a0, bz, az0, 0, 0, 0);
            az1 = __builtin_amdgcn_mfma_f32_32x32x16_bf16(a1, bz, az1, 0, 0, 0);
            if (kc < 256){
                anx0 = __builtin_amdgcn_mfma_f32_32x32x16_bf16(a0, bn, anx0, 0, 0, 0);
                anx1 = __builtin_amdgcn_mfma_f32_32x32x16_bf16(a1, bn, anx1, 0, 0, 0);
            } else {
                anh0 = __builtin_amdgcn_mfma_f32_32x32x16_bf16(a0, bn, anh0, 0, 0, 0);
                anh1 = __builtin_amdgcn_mfma_f32_32x32x16_bf16(a1, bn, anh1, 0, 0, 0);
            }
        }
    }
    float bir = bih[cg], biz = bih[256 + cg], bin = bih[512 + cg];
    float bhr = bhh[cg], bhz = bhh[256 + cg], bhn = bhh[512 + cg];
    float rb = bir + bhr, zb = biz + bhz;
#define GRU_EPI(VR, VZ, VNX, VNH, MSOFF)                                        \
    _Pragma("unroll")                                                           \
    for (int r = 0; r < 16; ++r){                                               \
        int row = (r & 3) + 8 * (r >> 2) + 4 * half + (MSOFF);                  \
        int m = m0 + row;                                                       \
        if (m < N_DSTN){                                                        \
            float h0v = H0[(size_t)m * 256 + cg];                               \
            float rr = 1.f / (1.f + __expf(-((VR)[r] + rb)));                   \
            float zz = 1.f / (1.f + __expf(-((VZ)[r] + zb)));                   \
            float nx = (VNX)[r] + bin + rr * ((VNH)[r] + bhn);                  \
            float tm = __expf(-2.f * fabsf(nx));                                \
            float nn = (1.f - tm) / (1.f + tm);                                 \
            nn = (nx >= 0.f) ? nn : -nn;                                        \
            outH[(size_t)m * 256 + cg] = (1.f - zz) * nn + zz * h0v;            \
        }                                                                       \
    }
    GRU_EPI(ar0, az0, anx0, anh0, 0)
    GRU_EPI(ar1, az1, anx1, anh1, 32)
#undef GRU_EPI
}

// ---- logits = h @ W_out + b_out (float4 LDS) ------------------------------
__global__ __launch_bounds__(256) void logits_kernel(
        const float* __restrict__ H, const float* __restrict__ Wout,
        const float* __restrict__ bout, float* __restrict__ outL){
    __shared__ float Hl[16 * 260];
    __shared__ float Wl[16 * 260];               // transposed: Wl[j][c]
    int tid = threadIdx.x;
    int m0 = blockIdx.x * 16;
    #pragma unroll
    for (int i = 0; i < 4; ++i){
        int ci = tid + i * 256;                  // 16 rows x 64 float4
        int row = ci >> 6;
        int c4 = (ci & 63) << 2;
        int gr = m0 + row; if (gr >= N_DSTN) gr = N_DSTN - 1;
        float4 v = *reinterpret_cast<const float4*>(H + (size_t)gr * 256 + c4);
        float* dp = Hl + row * 260 + c4;
        dp[0] = v.x; dp[1] = v.y; dp[2] = v.z; dp[3] = v.w;
    }
    #pragma unroll
    for (int i = 0; i < 16; ++i){
        int ci = tid + i * 256;                  // 4096 = 256c x 16j
        int c = ci >> 4, j = ci & 15;
        Wl[j * 260 + c] = Wout[c * 16 + j];
    }
    __syncthreads();
    int row = tid >> 4, j = tid & 15;
    const float* hr = Hl + row * 260;
    const float* wr = Wl + j * 260;
    float acc = bout[j];
    #pragma unroll
    for (int c = 0; c < 256; c += 4){
        float4 hv = *reinterpret_cast<const float4*>(hr + c);
        float4 wv = *reinterpret_cast<const float4*>(wr + c);
        acc = fmaf(hv.x, wv.x, fmaf(hv.y, wv.y, fmaf(hv.z, wv.z, fmaf(hv.w, wv.w, acc))));
    }
    int m = m0 + row;
    if (m < N_DSTN) outL[m * 16 + j] = acc;
}

extern "C" void kernel_launch(void* const* d_in, const int* in_sizes, int n_in,
                              void* d_out, int out_size, void* d_ws, size_t ws_size,
                              hipStream_t stream){
    const float* feat_gt = (const float*)d_in[0];
    const float* feat_ag = (const float*)d_in[1];
    const float* h0      = (const float*)d_in[2];
    const int*   e_src   = (const int*)d_in[3];
    const int*   e_dst   = (const int*)d_in[4];
    const float* W_src   = (const float*)d_in[5];
    const float* b_src   = (const float*)d_in[6];
    const float* W_dst   = (const float*)d_in[7];
    const float* b_dst   = (const float*)d_in[8];
    const float* attn    = (const float*)d_in[9];
    const float* W_res   = (const float*)d_in[10];
    const float* b_res   = (const float*)d_in[11];
    const float* W_ih    = (const float*)d_in[12];
    const float* W_hh    = (const float*)d_in[13];
    const float* b_ih    = (const float*)d_in[14];
    const float* b_hh    = (const float*)d_in[15];
    const float* W_out   = (const float*)d_in[16];
    const float* b_out   = (const float*)d_in[17];

    float* outL = (float*)d_out;
    float* outH = outL + (size_t)N_DSTN * 16;

    char* ws = (char*)d_ws;
    size_t off = 0;
    auto alloc = [&](size_t bytes) -> void* {
        void* p = ws + off; off = (off + bytes + 255) & ~(size_t)255; return p;
    };
    unsigned short* fs   = (unsigned short*)alloc((size_t)N_SRCN * 256 * 2);
    unsigned short* fd   = (unsigned short*)alloc((size_t)N_DSTN * 256 * 2);
    unsigned short* res  = (unsigned short*)alloc((size_t)N_DSTN * 256 * 2);
    unsigned short* xb   = (unsigned short*)alloc((size_t)N_DSTN * 256 * 2);
    unsigned short* hb   = (unsigned short*)alloc((size_t)N_DSTN * 256 * 2);
    unsigned short* Wt2  = (unsigned short*)alloc(49152 * 2);
    unsigned short* Wf   = (unsigned short*)alloc(393216 * 2);
    int* deg    = (int*)alloc(N_DSTN * 4);
    int* ptr    = (int*)alloc(N_DSTN * 4);
    int* cursor = (int*)alloc(N_DSTN * 4);
    int* csr    = (int*)alloc((size_t)NE * 4);

    hipMemsetAsync(deg, 0, N_DSTN * 4, stream);
    pack_kernel<<<1728, 256, 0, stream>>>(W_src, W_dst, W_res, W_ih, W_hh, Wt2, Wf);
    convh_kernel<<<12500, 256, 0, stream>>>(h0, hb);

    dim3 pg(4, 782);
    proj_kernel<<<pg, 256, 0, stream>>>(feat_gt, Wt2, b_src, fs);
    proj_kernel<<<pg, 256, 0, stream>>>(feat_ag, Wt2 + 16384, b_dst, fd);
    proj_kernel<<<pg, 256, 0, stream>>>(feat_ag, Wt2 + 32768, b_res, res);

    degree_kernel<<<3125, 256, 0, stream>>>(e_dst, deg);
    scan_kernel<<<1, 1024, 0, stream>>>(deg, ptr, cursor);
    scatter_kernel<<<3125, 256, 0, stream>>>(e_src, e_dst, cursor, csr);
    aggregate_kernel<<<12500, 256, 0, stream>>>(fs, fd, res, attn, ptr, deg, csr, xb);

    gru_kernel<<<dim3(2, 782), 256, 0, stream>>>(xb, hb, h0, Wf, b_ih, b_hh, outH);
    logits_kernel<<<3125, 256, 0, stream>>>(outH, W_out, b_out, outL);
}

// Round 3
// 497.126 us; speedup vs baseline: 1.3937x; 1.2095x over previous
//
#include <hip/hip_runtime.h>
#include <stdint.h>

#define N_SRCN 50000
#define N_DSTN 50000
#define NE     800000
#define HIDN   256
#define NEG    0.2f

typedef __attribute__((ext_vector_type(8)))  short short8;
typedef __attribute__((ext_vector_type(16))) float float16v;

__device__ __forceinline__ float bf2f(unsigned short u){
    union { unsigned u32; float f; } c; c.u32 = ((unsigned)u) << 16; return c.f;
}
__device__ __forceinline__ unsigned short f2bf(float f){
    union { float f; unsigned u; } c; c.f = f;
    unsigned r = c.u + 0x7fffu + ((c.u >> 16) & 1u);
    return (unsigned short)(r >> 16);
}
__device__ __forceinline__ float4 ld4b(const unsigned short* p){
    uint2 u = *reinterpret_cast<const uint2*>(p);
    float4 r;
    r.x = bf2f((unsigned short)(u.x & 0xffff));
    r.y = bf2f((unsigned short)(u.x >> 16));
    r.z = bf2f((unsigned short)(u.y & 0xffff));
    r.w = bf2f((unsigned short)(u.y >> 16));
    return r;
}

// ---- pack weights, input-indexed (coalesced reads, scattered 2B writes) ----
// Wt2: [which(3)][cb(8)][kk(4)][lane(64)][8]   (49152)
// Wf : [g(3)][cb(8)][kk(32)][lane(64)][8]      (393216), K=512 = [Wih|Whh]
__global__ void pack_kernel(const float* __restrict__ Wsrc, const float* __restrict__ Wdst,
                            const float* __restrict__ Wres, const float* __restrict__ Wih,
                            const float* __restrict__ Whh,
                            unsigned short* __restrict__ Wt2,
                            unsigned short* __restrict__ Wf){
    int i = blockIdx.x * 256 + threadIdx.x;
    if (i < 49152){
        int which = i >> 14, j = i & 16383;          // j = k*256 + c
        int k = j >> 8, c = j & 255;
        const float* W = (which == 0) ? Wsrc : (which == 1 ? Wdst : Wres);
        float v = W[j];
        int off = which * 16384 + (c >> 5) * 2048 + (k >> 4) * 512
                + (((k >> 3) & 1) * 32 + (c & 31)) * 8 + (k & 7);
        Wt2[off] = f2bf(v);
    } else if (i < 49152 + 196608){
        int o = i - 49152;                            // Wih flat: (g*256+c)*256+k
        int row = o >> 8, k = o & 255;
        int g = row >> 8, c = row & 255;
        float v = Wih[o];
        int off = g * 131072 + (c >> 5) * 16384 + (k >> 4) * 512
                + (((k >> 3) & 1) * 32 + (c & 31)) * 8 + (k & 7);
        Wf[off] = f2bf(v);
    } else if (i < 49152 + 393216){
        int o = i - 49152 - 196608;                   // Whh
        int row = o >> 8, k = o & 255;
        int g = row >> 8, c = row & 255;
        float v = Whh[o];
        int off = g * 131072 + (c >> 5) * 16384 + (16 + (k >> 4)) * 512
                + (((k >> 3) & 1) * 32 + (c & 31)) * 8 + (k & 7);
        Wf[off] = f2bf(v);
    }
}

// ---- h0 f32 -> bf16 -------------------------------------------------------
__global__ void convh_kernel(const float* __restrict__ h, unsigned short* __restrict__ hb){
    int i = blockIdx.x * 256 + threadIdx.x;
    if (i < N_DSTN * 64){
        float4 v = reinterpret_cast<const float4*>(h)[i];
        uint2 o;
        o.x = (unsigned)f2bf(v.x) | ((unsigned)f2bf(v.y) << 16);
        o.y = (unsigned)f2bf(v.z) | ((unsigned)f2bf(v.w) << 16);
        reinterpret_cast<uint2*>(hb)[i] = o;
    }
}

// ---- projection GEMM (K=64), LDS C-staging for coalesced stores -----------
__global__ __launch_bounds__(256) void proj_kernel(
        const float* __restrict__ A, const unsigned short* __restrict__ Wt2,
        const float* __restrict__ bias, unsigned short* __restrict__ out){
    __shared__ unsigned short As[64 * 72];
    __shared__ unsigned short Cs[64 * 72];
    int tid = threadIdx.x;
    int m0 = blockIdx.y * 64;
    #pragma unroll
    for (int i = 0; i < 4; ++i){
        int ci = tid + i * 256;
        int row = ci >> 4;
        int k4 = (ci & 15) << 2;
        int gr = m0 + row; if (gr >= N_SRCN) gr = N_SRCN - 1;
        float4 v = *reinterpret_cast<const float4*>(A + (size_t)gr * 64 + k4);
        unsigned short* dp = As + row * 72 + k4;
        dp[0] = f2bf(v.x); dp[1] = f2bf(v.y); dp[2] = f2bf(v.z); dp[3] = f2bf(v.w);
    }
    __syncthreads();
    int lane = tid & 63, w = tid >> 6;
    int l31 = lane & 31, half = lane >> 5;
    int msub = (w & 1) * 32;
    int cbw = blockIdx.x * 2 + (w >> 1);
    const unsigned short* bb = Wt2 + cbw * 2048 + lane * 8;
    const unsigned short* ap = As + (msub + l31) * 72 + half * 8;
    float16v acc = {0,0,0,0,0,0,0,0,0,0,0,0,0,0,0,0};
    #pragma unroll
    for (int ks = 0; ks < 4; ++ks){
        short8 a = *reinterpret_cast<const short8*>(ap + ks * 16);
        short8 b = *reinterpret_cast<const short8*>(bb + ks * 512);
        acc = __builtin_amdgcn_mfma_f32_32x32x16_bf16(a, b, acc, 0, 0, 0);
    }
    float bv = bias[cbw * 32 + l31];
    int ccol = (w >> 1) * 32 + l31;
    #pragma unroll
    for (int r = 0; r < 16; ++r){
        int row = (r & 3) + 8 * (r >> 2) + 4 * half + msub;
        Cs[row * 72 + ccol] = f2bf(acc[r] + bv);
    }
    __syncthreads();
    int srow = tid >> 2, chunk = tid & 3;
    int gr2 = m0 + srow;
    if (gr2 < N_SRCN){
        const uint4* sp = reinterpret_cast<const uint4*>(Cs + srow * 72 + chunk * 16);
        uint4* gp = reinterpret_cast<uint4*>(out + (size_t)gr2 * 256 + blockIdx.x * 64 + chunk * 16);
        gp[0] = sp[0];
        gp[1] = sp[1];
    }
}

// ---- edge CSR build -------------------------------------------------------
__global__ void degree_kernel(const int* __restrict__ dst, int* __restrict__ deg){
    int i = blockIdx.x * 256 + threadIdx.x;
    if (i < NE) atomicAdd(&deg[dst[i]], 1);
}

__global__ void scan1_kernel(const int* __restrict__ deg, int* __restrict__ bsum){
    __shared__ int s[256];
    int tid = threadIdx.x;
    int i = blockIdx.x * 256 + tid;
    s[tid] = (i < N_DSTN) ? deg[i] : 0;
    __syncthreads();
    #pragma unroll
    for (int off = 128; off; off >>= 1){
        if (tid < off) s[tid] += s[tid + off];
        __syncthreads();
    }
    if (tid == 0) bsum[blockIdx.x] = s[0];
}

__global__ void scan2_kernel(const int* __restrict__ bsum, int* __restrict__ boff){
    __shared__ int s[256];
    int tid = threadIdx.x;
    int v = (tid < 196) ? bsum[tid] : 0;
    s[tid] = v;
    __syncthreads();
    #pragma unroll
    for (int off = 1; off < 256; off <<= 1){
        int t = (tid >= off) ? s[tid - off] : 0;
        __syncthreads();
        s[tid] += t;
        __syncthreads();
    }
    if (tid < 196) boff[tid] = s[tid] - v;
}

__global__ void scan3_kernel(const int* __restrict__ deg, const int* __restrict__ boff,
                             int* __restrict__ ptr, int* __restrict__ cursor){
    __shared__ int s[256];
    int tid = threadIdx.x;
    int i = blockIdx.x * 256 + tid;
    int v = (i < N_DSTN) ? deg[i] : 0;
    s[tid] = v;
    __syncthreads();
    #pragma unroll
    for (int off = 1; off < 256; off <<= 1){
        int t = (tid >= off) ? s[tid - off] : 0;
        __syncthreads();
        s[tid] += t;
        __syncthreads();
    }
    int ex = s[tid] - v + boff[blockIdx.x];
    if (i < N_DSTN){ ptr[i] = ex; cursor[i] = ex; }
}

__global__ void scatter_kernel(const int* __restrict__ src, const int* __restrict__ dst,
                               int* __restrict__ cursor, int* __restrict__ csr){
    int i = blockIdx.x * 256 + threadIdx.x;
    if (i < NE){
        int d = dst[i];
        int pos = atomicAdd(&cursor[d], 1);
        csr[pos] = src[i];
    }
}

// ---- per-dst aggregation, no online max (exp safe here), 4-deep pipeline --
__global__ __launch_bounds__(256) void aggregate_kernel(
        const unsigned short* __restrict__ fs, const unsigned short* __restrict__ fd,
        const unsigned short* __restrict__ res, const float* __restrict__ attn,
        const int* __restrict__ ptr, const int* __restrict__ deg,
        const int* __restrict__ csr, unsigned short* __restrict__ x){
    int wv = threadIdx.x >> 6;
    int d = blockIdx.x * 4 + wv;
    if (d >= N_DSTN) return;
    int lane = threadIdx.x & 63;
    int c4 = lane * 4;
    float4 fdv = ld4b(fd + (size_t)d * 256 + c4);
    float4 at = *reinterpret_cast<const float4*>(attn + (lane >> 4) * 64 + (lane & 15) * 4);
    int p = ptr[d], dg = deg[d];
    float l = 0.f;
    float4 acc = make_float4(0.f, 0.f, 0.f, 0.f);
    for (int base = 0; base < dg; base += 64){
        int cnt = min(64, dg - base);
        int sreg = (lane < cnt) ? csr[p + base + lane] : 0;
        float4 b0 = ld4b(fs + (size_t)__shfl(sreg, 0) * 256 + c4);
        float4 b1 = ld4b(fs + (size_t)__shfl(sreg, 1 & 63) * 256 + c4);
        float4 b2 = ld4b(fs + (size_t)__shfl(sreg, 2 & 63) * 256 + c4);
        float4 b3 = ld4b(fs + (size_t)__shfl(sreg, 3 & 63) * 256 + c4);
        for (int j = 0; j < cnt; j += 4){
            float4 n0 = ld4b(fs + (size_t)__shfl(sreg, (j + 4) & 63) * 256 + c4);
            float4 n1 = ld4b(fs + (size_t)__shfl(sreg, (j + 5) & 63) * 256 + c4);
            float4 n2 = ld4b(fs + (size_t)__shfl(sreg, (j + 6) & 63) * 256 + c4);
            float4 n3 = ld4b(fs + (size_t)__shfl(sreg, (j + 7) & 63) * 256 + c4);
#define PROC(BV, T) { \
            float ex = BV.x + fdv.x; ex = ex > 0.f ? ex : NEG * ex; \
            float ey = BV.y + fdv.y; ey = ey > 0.f ? ey : NEG * ey; \
            float ez = BV.z + fdv.z; ez = ez > 0.f ? ez : NEG * ez; \
            float ew = BV.w + fdv.w; ew = ew > 0.f ? ew : NEG * ew; \
            float part = ex * at.x + ey * at.y + ez * at.z + ew * at.w; \
            part += __shfl_xor(part, 1); \
            part += __shfl_xor(part, 2); \
            part += __shfl_xor(part, 4); \
            part += __shfl_xor(part, 8); \
            float wgt = ((j + (T)) < cnt) ? __expf(part) : 0.f; \
            l += wgt; \
            acc.x = fmaf(wgt, BV.x, acc.x); \
            acc.y = fmaf(wgt, BV.y, acc.y); \
            acc.z = fmaf(wgt, BV.z, acc.z); \
            acc.w = fmaf(wgt, BV.w, acc.w); }
            PROC(b0, 0) PROC(b1, 1) PROC(b2, 2) PROC(b3, 3)
#undef PROC
            b0 = n0; b1 = n1; b2 = n2; b3 = n3;
        }
    }
    float inv = (l > 0.f) ? 1.f / l : 0.f;
    float4 rv = ld4b(res + (size_t)d * 256 + c4);
    float xx = fmaxf(fmaf(acc.x, inv, rv.x), 0.f);
    float xy = fmaxf(fmaf(acc.y, inv, rv.y), 0.f);
    float xz = fmaxf(fmaf(acc.z, inv, rv.z), 0.f);
    float xw = fmaxf(fmaf(acc.w, inv, rv.w), 0.f);
    uint2 o;
    o.x = (unsigned)f2bf(xx) | ((unsigned)f2bf(xy) << 16);
    o.y = (unsigned)f2bf(xz) | ((unsigned)f2bf(xw) << 16);
    *reinterpret_cast<uint2*>(x + (size_t)d * 256 + c4) = o;
}

// ---- GRU v3: 128 rows x 32 cols/block, 4 acc tiles/wave, B shared via L1 --
__global__ __launch_bounds__(256, 3) void gru_kernel(
        const unsigned short* __restrict__ Xb, const unsigned short* __restrict__ Hb,
        const float* __restrict__ H0, const unsigned short* __restrict__ Wf,
        const float* __restrict__ bih, const float* __restrict__ bhh,
        float* __restrict__ outH){
    __shared__ unsigned short As[128 * 136];
    int tid = threadIdx.x;
    int m0 = blockIdx.y * 128;
    int w = tid >> 6, lane = tid & 63;
    int l31 = lane & 31, half = lane >> 5;
    int cb = blockIdx.x;                          // 0..7
    int cg = cb * 32 + l31;
    const unsigned short* bb = Wf + cb * 16384 + lane * 8;
    float16v ar  = {0,0,0,0,0,0,0,0,0,0,0,0,0,0,0,0};
    float16v az = ar, anx = ar, anh = ar;
    #pragma unroll
    for (int kc = 0; kc < 512; kc += 128){
        const unsigned short* srcb = (kc < 256) ? (Xb + kc) : (Hb + (kc - 256));
        __syncthreads();
        #pragma unroll
        for (int i = 0; i < 8; ++i){
            int ci = tid + i * 256;               // 2048 chunks: 128 rows x 16 x 16B
            int row = ci >> 4;
            int k8 = (ci & 15) << 3;
            int gr = m0 + row; if (gr >= N_DSTN) gr = N_DSTN - 1;
            *reinterpret_cast<uint4*>(As + row * 136 + k8) =
                *reinterpret_cast<const uint4*>(srcb + (size_t)gr * 256 + k8);
        }
        __syncthreads();
        const unsigned short* ap = As + (w * 32 + l31) * 136 + half * 8;
        #pragma unroll
        for (int ks = 0; ks < 8; ++ks){
            int kk = (kc >> 4) + ks;              // 0..31
            short8 a  = *reinterpret_cast<const short8*>(ap + ks * 16);
            short8 br = *reinterpret_cast<const short8*>(bb + (size_t)kk * 512);
            short8 bz = *reinterpret_cast<const short8*>(bb + 131072 + (size_t)kk * 512);
            short8 bn = *reinterpret_cast<const short8*>(bb + 262144 + (size_t)kk * 512);
            ar = __builtin_amdgcn_mfma_f32_32x32x16_bf16(a, br, ar, 0, 0, 0);
            az = __builtin_amdgcn_mfma_f32_32x32x16_bf16(a, bz, az, 0, 0, 0);
            if (kc < 256) anx = __builtin_amdgcn_mfma_f32_32x32x16_bf16(a, bn, anx, 0, 0, 0);
            else          anh = __builtin_amdgcn_mfma_f32_32x32x16_bf16(a, bn, anh, 0, 0, 0);
        }
    }
    float rb = bih[cg] + bhh[cg];
    float zb = bih[256 + cg] + bhh[256 + cg];
    float bin = bih[512 + cg], bhn = bhh[512 + cg];
    #pragma unroll
    for (int r = 0; r < 16; ++r){
        int m = m0 + w * 32 + (r & 3) + 8 * (r >> 2) + 4 * half;
        if (m < N_DSTN){
            float h0v = H0[(size_t)m * 256 + cg];
            float rr = 1.f / (1.f + __expf(-(ar[r] + rb)));
            float zz = 1.f / (1.f + __expf(-(az[r] + zb)));
            float nx = anx[r] + bin + rr * (anh[r] + bhn);
            float tm = __expf(-2.f * fabsf(nx));
            float nn = (1.f - tm) / (1.f + tm);
            nn = (nx >= 0.f) ? nn : -nn;
            outH[(size_t)m * 256 + cg] = (1.f - zz) * nn + zz * h0v;
        }
    }
}

// ---- logits = h @ W_out + b_out ------------------------------------------
__global__ __launch_bounds__(256) void logits_kernel(
        const float* __restrict__ H, const float* __restrict__ Wout,
        const float* __restrict__ bout, float* __restrict__ outL){
    __shared__ float Hl[16 * 260];
    __shared__ float Wl[16 * 260];
    int tid = threadIdx.x;
    int m0 = blockIdx.x * 16;
    #pragma unroll
    for (int i = 0; i < 4; ++i){
        int ci = tid + i * 256;
        int row = ci >> 6;
        int c4 = (ci & 63) << 2;
        int gr = m0 + row; if (gr >= N_DSTN) gr = N_DSTN - 1;
        float4 v = *reinterpret_cast<const float4*>(H + (size_t)gr * 256 + c4);
        float* dp = Hl + row * 260 + c4;
        dp[0] = v.x; dp[1] = v.y; dp[2] = v.z; dp[3] = v.w;
    }
    #pragma unroll
    for (int i = 0; i < 16; ++i){
        int ci = tid + i * 256;
        int c = ci >> 4, j = ci & 15;
        Wl[j * 260 + c] = Wout[c * 16 + j];
    }
    __syncthreads();
    int row = tid >> 4, j = tid & 15;
    const float* hr = Hl + row * 260;
    const float* wr = Wl + j * 260;
    float acc = bout[j];
    #pragma unroll
    for (int c = 0; c < 256; c += 4){
        float4 hv = *reinterpret_cast<const float4*>(hr + c);
        float4 wv = *reinterpret_cast<const float4*>(wr + c);
        acc = fmaf(hv.x, wv.x, fmaf(hv.y, wv.y, fmaf(hv.z, wv.z, fmaf(hv.w, wv.w, acc))));
    }
    int m = m0 + row;
    if (m < N_DSTN) outL[m * 16 + j] = acc;
}

extern "C" void kernel_launch(void* const* d_in, const int* in_sizes, int n_in,
                              void* d_out, int out_size, void* d_ws, size_t ws_size,
                              hipStream_t stream){
    const float* feat_gt = (const float*)d_in[0];
    const float* feat_ag = (const float*)d_in[1];
    const float* h0      = (const float*)d_in[2];
    const int*   e_src   = (const int*)d_in[3];
    const int*   e_dst   = (const int*)d_in[4];
    const float* W_src   = (const float*)d_in[5];
    const float* b_src   = (const float*)d_in[6];
    const float* W_dst   = (const float*)d_in[7];
    const float* b_dst   = (const float*)d_in[8];
    const float* attn    = (const float*)d_in[9];
    const float* W_res   = (const float*)d_in[10];
    const float* b_res   = (const float*)d_in[11];
    const float* W_ih    = (const float*)d_in[12];
    const float* W_hh    = (const float*)d_in[13];
    const float* b_ih    = (const float*)d_in[14];
    const float* b_hh    = (const float*)d_in[15];
    const float* W_out   = (const float*)d_in[16];
    const float* b_out   = (const float*)d_in[17];

    float* outL = (float*)d_out;
    float* outH = outL + (size_t)N_DSTN * 16;

    char* ws = (char*)d_ws;
    size_t off = 0;
    auto alloc = [&](size_t bytes) -> void* {
        void* p = ws + off; off = (off + bytes + 255) & ~(size_t)255; return p;
    };
    unsigned short* fs   = (unsigned short*)alloc((size_t)N_SRCN * 256 * 2);
    unsigned short* fd   = (unsigned short*)alloc((size_t)N_DSTN * 256 * 2);
    unsigned short* res  = (unsigned short*)alloc((size_t)N_DSTN * 256 * 2);
    unsigned short* xb   = (unsigned short*)alloc((size_t)N_DSTN * 256 * 2);
    unsigned short* hb   = (unsigned short*)alloc((size_t)N_DSTN * 256 * 2);
    unsigned short* Wt2  = (unsigned short*)alloc(49152 * 2);
    unsigned short* Wf   = (unsigned short*)alloc(393216 * 2);
    int* deg    = (int*)alloc(N_DSTN * 4);
    int* ptr    = (int*)alloc(N_DSTN * 4);
    int* cursor = (int*)alloc(N_DSTN * 4);
    int* csr    = (int*)alloc((size_t)NE * 4);
    int* bsum   = (int*)alloc(256 * 4);
    int* boff   = (int*)alloc(256 * 4);

    hipMemsetAsync(deg, 0, N_DSTN * 4, stream);
    pack_kernel<<<1728, 256, 0, stream>>>(W_src, W_dst, W_res, W_ih, W_hh, Wt2, Wf);
    convh_kernel<<<12500, 256, 0, stream>>>(h0, hb);

    dim3 pg(4, 782);
    proj_kernel<<<pg, 256, 0, stream>>>(feat_gt, Wt2, b_src, fs);
    proj_kernel<<<pg, 256, 0, stream>>>(feat_ag, Wt2 + 16384, b_dst, fd);
    proj_kernel<<<pg, 256, 0, stream>>>(feat_ag, Wt2 + 32768, b_res, res);

    degree_kernel<<<3125, 256, 0, stream>>>(e_dst, deg);
    scan1_kernel<<<196, 256, 0, stream>>>(deg, bsum);
    scan2_kernel<<<1, 256, 0, stream>>>(bsum, boff);
    scan3_kernel<<<196, 256, 0, stream>>>(deg, boff, ptr, cursor);
    scatter_kernel<<<3125, 256, 0, stream>>>(e_src, e_dst, cursor, csr);
    aggregate_kernel<<<12500, 256, 0, stream>>>(fs, fd, res, attn, ptr, deg, csr, xb);

    gru_kernel<<<dim3(8, 391), 256, 0, stream>>>(xb, hb, h0, Wf, b_ih, b_hh, outH);
    logits_kernel<<<3125, 256, 0, stream>>>(outH, W_out, b_out, outL);
}

// Round 4
// 485.154 us; speedup vs baseline: 1.4281x; 1.0247x over previous
//
#include <hip/hip_runtime.h>
#include <stdint.h>

#define N_SRCN 50000
#define N_DSTN 50000
#define NE     800000
#define HIDN   256
#define NEG    0.2f

typedef __attribute__((ext_vector_type(8)))  short short8;
typedef __attribute__((ext_vector_type(16))) float float16v;

__device__ __forceinline__ float bf2f(unsigned short u){
    union { unsigned u32; float f; } c; c.u32 = ((unsigned)u) << 16; return c.f;
}
__device__ __forceinline__ unsigned short f2bf(float f){
    union { float f; unsigned u; } c; c.f = f;
    unsigned r = c.u + 0x7fffu + ((c.u >> 16) & 1u);
    return (unsigned short)(r >> 16);
}
__device__ __forceinline__ float4 ld4b(const unsigned short* p){
    uint2 u = *reinterpret_cast<const uint2*>(p);
    float4 r;
    r.x = bf2f((unsigned short)(u.x & 0xffff));
    r.y = bf2f((unsigned short)(u.x >> 16));
    r.z = bf2f((unsigned short)(u.y & 0xffff));
    r.w = bf2f((unsigned short)(u.y >> 16));
    return r;
}

// ---- pack weights, input-indexed (coalesced reads, scattered 2B writes) ----
// Wt2: [which(3)][cb(8)][kk(4)][lane(64)][8]   (49152)
// Wf : [g(3)][cb(8)][kk(32)][lane(64)][8]      (393216), K=512 = [Wih|Whh]
__global__ void pack_kernel(const float* __restrict__ Wsrc, const float* __restrict__ Wdst,
                            const float* __restrict__ Wres, const float* __restrict__ Wih,
                            const float* __restrict__ Whh,
                            unsigned short* __restrict__ Wt2,
                            unsigned short* __restrict__ Wf){
    int i = blockIdx.x * 256 + threadIdx.x;
    if (i < 49152){
        int which = i >> 14, j = i & 16383;          // j = k*256 + c
        int k = j >> 8, c = j & 255;
        const float* W = (which == 0) ? Wsrc : (which == 1 ? Wdst : Wres);
        float v = W[j];
        int off = which * 16384 + (c >> 5) * 2048 + (k >> 4) * 512
                + (((k >> 3) & 1) * 32 + (c & 31)) * 8 + (k & 7);
        Wt2[off] = f2bf(v);
    } else if (i < 49152 + 196608){
        int o = i - 49152;                            // Wih flat: (g*256+c)*256+k
        int row = o >> 8, k = o & 255;
        int g = row >> 8, c = row & 255;
        float v = Wih[o];
        int off = g * 131072 + (c >> 5) * 16384 + (k >> 4) * 512
                + (((k >> 3) & 1) * 32 + (c & 31)) * 8 + (k & 7);
        Wf[off] = f2bf(v);
    } else if (i < 49152 + 393216){
        int o = i - 49152 - 196608;                   // Whh
        int row = o >> 8, k = o & 255;
        int g = row >> 8, c = row & 255;
        float v = Whh[o];
        int off = g * 131072 + (c >> 5) * 16384 + (16 + (k >> 4)) * 512
                + (((k >> 3) & 1) * 32 + (c & 31)) * 8 + (k & 7);
        Wf[off] = f2bf(v);
    }
}

// ---- fused projection GEMM (K=64), z selects {src, dst, res} --------------
__global__ __launch_bounds__(256) void proj_kernel(
        const float* __restrict__ Agt, const float* __restrict__ Aag,
        const unsigned short* __restrict__ Wt2,
        const float* __restrict__ bsrc, const float* __restrict__ bdst,
        const float* __restrict__ bres,
        unsigned short* __restrict__ fs, unsigned short* __restrict__ fd,
        unsigned short* __restrict__ resb){
    __shared__ unsigned short As[64 * 72];
    __shared__ unsigned short Cs[64 * 72];
    int z = blockIdx.z;
    const float* A = (z == 0) ? Agt : Aag;
    const float* bias = (z == 0) ? bsrc : (z == 1 ? bdst : bres);
    unsigned short* out = (z == 0) ? fs : (z == 1 ? fd : resb);
    const unsigned short* Wb = Wt2 + z * 16384;
    int tid = threadIdx.x;
    int m0 = blockIdx.y * 64;
    #pragma unroll
    for (int i = 0; i < 4; ++i){
        int ci = tid + i * 256;
        int row = ci >> 4;
        int k4 = (ci & 15) << 2;
        int gr = m0 + row; if (gr >= N_SRCN) gr = N_SRCN - 1;
        float4 v = *reinterpret_cast<const float4*>(A + (size_t)gr * 64 + k4);
        unsigned short* dp = As + row * 72 + k4;
        dp[0] = f2bf(v.x); dp[1] = f2bf(v.y); dp[2] = f2bf(v.z); dp[3] = f2bf(v.w);
    }
    __syncthreads();
    int lane = tid & 63, w = tid >> 6;
    int l31 = lane & 31, half = lane >> 5;
    int msub = (w & 1) * 32;
    int cbw = blockIdx.x * 2 + (w >> 1);
    const unsigned short* bb = Wb + cbw * 2048 + lane * 8;
    const unsigned short* ap = As + (msub + l31) * 72 + half * 8;
    float16v acc = {0,0,0,0,0,0,0,0,0,0,0,0,0,0,0,0};
    #pragma unroll
    for (int ks = 0; ks < 4; ++ks){
        short8 a = *reinterpret_cast<const short8*>(ap + ks * 16);
        short8 b = *reinterpret_cast<const short8*>(bb + ks * 512);
        acc = __builtin_amdgcn_mfma_f32_32x32x16_bf16(a, b, acc, 0, 0, 0);
    }
    float bv = bias[cbw * 32 + l31];
    int ccol = (w >> 1) * 32 + l31;
    #pragma unroll
    for (int r = 0; r < 16; ++r){
        int row = (r & 3) + 8 * (r >> 2) + 4 * half + msub;
        Cs[row * 72 + ccol] = f2bf(acc[r] + bv);
    }
    __syncthreads();
    int srow = tid >> 2, chunk = tid & 3;
    int gr2 = m0 + srow;
    if (gr2 < N_SRCN){
        const uint4* sp = reinterpret_cast<const uint4*>(Cs + srow * 72 + chunk * 16);
        uint4* gp = reinterpret_cast<uint4*>(out + (size_t)gr2 * 256 + blockIdx.x * 64 + chunk * 16);
        gp[0] = sp[0];
        gp[1] = sp[1];
    }
}

// ---- edge CSR build -------------------------------------------------------
__global__ void degree_kernel(const int* __restrict__ dst, int* __restrict__ deg){
    int i = blockIdx.x * 256 + threadIdx.x;
    if (i < NE) atomicAdd(&deg[dst[i]], 1);
}

__global__ void scan1_kernel(const int* __restrict__ deg, int* __restrict__ bsum){
    __shared__ int s[256];
    int tid = threadIdx.x;
    int i = blockIdx.x * 256 + tid;
    s[tid] = (i < N_DSTN) ? deg[i] : 0;
    __syncthreads();
    #pragma unroll
    for (int off = 128; off; off >>= 1){
        if (tid < off) s[tid] += s[tid + off];
        __syncthreads();
    }
    if (tid == 0) bsum[blockIdx.x] = s[0];
}

__global__ void scan2_kernel(const int* __restrict__ bsum, int* __restrict__ boff){
    __shared__ int s[256];
    int tid = threadIdx.x;
    int v = (tid < 196) ? bsum[tid] : 0;
    s[tid] = v;
    __syncthreads();
    #pragma unroll
    for (int off = 1; off < 256; off <<= 1){
        int t = (tid >= off) ? s[tid - off] : 0;
        __syncthreads();
        s[tid] += t;
        __syncthreads();
    }
    if (tid < 196) boff[tid] = s[tid] - v;
}

__global__ void scan3_kernel(const int* __restrict__ deg, const int* __restrict__ boff,
                             int* __restrict__ ptr, int* __restrict__ cursor){
    __shared__ int s[256];
    int tid = threadIdx.x;
    int i = blockIdx.x * 256 + tid;
    int v = (i < N_DSTN) ? deg[i] : 0;
    s[tid] = v;
    __syncthreads();
    #pragma unroll
    for (int off = 1; off < 256; off <<= 1){
        int t = (tid >= off) ? s[tid - off] : 0;
        __syncthreads();
        s[tid] += t;
        __syncthreads();
    }
    int ex = s[tid] - v + boff[blockIdx.x];
    if (i < N_DSTN){ ptr[i] = ex; cursor[i] = ex; }
}

__global__ void scatter_kernel(const int* __restrict__ src, const int* __restrict__ dst,
                               int* __restrict__ cursor, int* __restrict__ csr){
    int i = blockIdx.x * 256 + threadIdx.x;
    if (i < NE){
        int d = dst[i];
        int pos = atomicAdd(&cursor[d], 1);
        csr[pos] = src[i];
    }
}

// ---- per-dst aggregation, no online max (exp safe here), 4-deep pipeline --
__global__ __launch_bounds__(256) void aggregate_kernel(
        const unsigned short* __restrict__ fs, const unsigned short* __restrict__ fd,
        const unsigned short* __restrict__ res, const float* __restrict__ attn,
        const int* __restrict__ ptr, const int* __restrict__ deg,
        const int* __restrict__ csr, unsigned short* __restrict__ x){
    int wv = threadIdx.x >> 6;
    int d = blockIdx.x * 4 + wv;
    if (d >= N_DSTN) return;
    int lane = threadIdx.x & 63;
    int c4 = lane * 4;
    float4 fdv = ld4b(fd + (size_t)d * 256 + c4);
    float4 at = *reinterpret_cast<const float4*>(attn + (lane >> 4) * 64 + (lane & 15) * 4);
    int p = ptr[d], dg = deg[d];
    float l = 0.f;
    float4 acc = make_float4(0.f, 0.f, 0.f, 0.f);
    for (int base = 0; base < dg; base += 64){
        int cnt = min(64, dg - base);
        int sreg = (lane < cnt) ? csr[p + base + lane] : 0;
        float4 b0 = ld4b(fs + (size_t)__shfl(sreg, 0) * 256 + c4);
        float4 b1 = ld4b(fs + (size_t)__shfl(sreg, 1 & 63) * 256 + c4);
        float4 b2 = ld4b(fs + (size_t)__shfl(sreg, 2 & 63) * 256 + c4);
        float4 b3 = ld4b(fs + (size_t)__shfl(sreg, 3 & 63) * 256 + c4);
        for (int j = 0; j < cnt; j += 4){
            float4 n0 = ld4b(fs + (size_t)__shfl(sreg, (j + 4) & 63) * 256 + c4);
            float4 n1 = ld4b(fs + (size_t)__shfl(sreg, (j + 5) & 63) * 256 + c4);
            float4 n2 = ld4b(fs + (size_t)__shfl(sreg, (j + 6) & 63) * 256 + c4);
            float4 n3 = ld4b(fs + (size_t)__shfl(sreg, (j + 7) & 63) * 256 + c4);
#define PROC(BV, T) { \
            float ex = BV.x + fdv.x; ex = ex > 0.f ? ex : NEG * ex; \
            float ey = BV.y + fdv.y; ey = ey > 0.f ? ey : NEG * ey; \
            float ez = BV.z + fdv.z; ez = ez > 0.f ? ez : NEG * ez; \
            float ew = BV.w + fdv.w; ew = ew > 0.f ? ew : NEG * ew; \
            float part = ex * at.x + ey * at.y + ez * at.z + ew * at.w; \
            part += __shfl_xor(part, 1); \
            part += __shfl_xor(part, 2); \
            part += __shfl_xor(part, 4); \
            part += __shfl_xor(part, 8); \
            float wgt = ((j + (T)) < cnt) ? __expf(part) : 0.f; \
            l += wgt; \
            acc.x = fmaf(wgt, BV.x, acc.x); \
            acc.y = fmaf(wgt, BV.y, acc.y); \
            acc.z = fmaf(wgt, BV.z, acc.z); \
            acc.w = fmaf(wgt, BV.w, acc.w); }
            PROC(b0, 0) PROC(b1, 1) PROC(b2, 2) PROC(b3, 3)
#undef PROC
            b0 = n0; b1 = n1; b2 = n2; b3 = n3;
        }
    }
    float inv = (l > 0.f) ? 1.f / l : 0.f;
    float4 rv = ld4b(res + (size_t)d * 256 + c4);
    float xx = fmaxf(fmaf(acc.x, inv, rv.x), 0.f);
    float xy = fmaxf(fmaf(acc.y, inv, rv.y), 0.f);
    float xz = fmaxf(fmaf(acc.z, inv, rv.z), 0.f);
    float xw = fmaxf(fmaf(acc.w, inv, rv.w), 0.f);
    uint2 o;
    o.x = (unsigned)f2bf(xx) | ((unsigned)f2bf(xy) << 16);
    o.y = (unsigned)f2bf(xz) | ((unsigned)f2bf(xw) << 16);
    *reinterpret_cast<uint2*>(x + (size_t)d * 256 + c4) = o;
}

// ---- GRU v4: XCD-swizzled 128x32 blocks, H staged from f32, 4 acc tiles ---
// blockIdx.x decode: xcd = id&7 (hw round-robin), r = id>>3;
// strip = xcd*49 + (r>>3)  (49 strips per XCD), cb = r&7.
// All 8 cb-blocks of a strip run temporally adjacent on ONE XCD -> A hits L2.
__global__ __launch_bounds__(256, 4) void gru_kernel(
        const unsigned short* __restrict__ Xb,
        const float* __restrict__ H0, const unsigned short* __restrict__ Wf,
        const float* __restrict__ bih, const float* __restrict__ bhh,
        float* __restrict__ outH){
    __shared__ unsigned short As[128 * 136];
    int tid = threadIdx.x;
    int sid = blockIdx.x;
    int xcd = sid & 7, rr_ = sid >> 3;
    int strip = xcd * 49 + (rr_ >> 3);
    int cb = rr_ & 7;
    int m0 = strip << 7;
    int w = tid >> 6, lane = tid & 63;
    int l31 = lane & 31, half = lane >> 5;
    int cg = cb * 32 + l31;
    const unsigned short* bb = Wf + cb * 16384 + lane * 8;
    float16v ar  = {0,0,0,0,0,0,0,0,0,0,0,0,0,0,0,0};
    float16v az = ar, anx = ar, anh = ar;
    #pragma unroll
    for (int kc = 0; kc < 512; kc += 128){
        __syncthreads();
        if (kc < 256){
            #pragma unroll
            for (int i = 0; i < 8; ++i){
                int ci = tid + i * 256;           // 2048 chunks: 128 rows x 16 x 16B
                int row = ci >> 4;
                int k8 = (ci & 15) << 3;
                int gr = m0 + row; if (gr >= N_DSTN) gr = N_DSTN - 1;
                *reinterpret_cast<uint4*>(As + row * 136 + k8) =
                    *reinterpret_cast<const uint4*>(Xb + (size_t)gr * 256 + kc + k8);
            }
        } else {
            #pragma unroll
            for (int i = 0; i < 8; ++i){
                int ci = tid + i * 256;
                int row = ci >> 4;
                int k8 = (ci & 15) << 3;
                int gr = m0 + row; if (gr >= N_DSTN) gr = N_DSTN - 1;
                const float* hp = H0 + (size_t)gr * 256 + (kc - 256) + k8;
                float4 f0 = *reinterpret_cast<const float4*>(hp);
                float4 f1 = *reinterpret_cast<const float4*>(hp + 4);
                uint4 o;
                o.x = (unsigned)f2bf(f0.x) | ((unsigned)f2bf(f0.y) << 16);
                o.y = (unsigned)f2bf(f0.z) | ((unsigned)f2bf(f0.w) << 16);
                o.z = (unsigned)f2bf(f1.x) | ((unsigned)f2bf(f1.y) << 16);
                o.w = (unsigned)f2bf(f1.z) | ((unsigned)f2bf(f1.w) << 16);
                *reinterpret_cast<uint4*>(As + row * 136 + k8) = o;
            }
        }
        __syncthreads();
        const unsigned short* ap = As + (w * 32 + l31) * 136 + half * 8;
        #pragma unroll
        for (int ks = 0; ks < 8; ++ks){
            int kk = (kc >> 4) + ks;              // 0..31
            short8 a  = *reinterpret_cast<const short8*>(ap + ks * 16);
            short8 br = *reinterpret_cast<const short8*>(bb + (size_t)kk * 512);
            short8 bz = *reinterpret_cast<const short8*>(bb + 131072 + (size_t)kk * 512);
            short8 bn = *reinterpret_cast<const short8*>(bb + 262144 + (size_t)kk * 512);
            ar = __builtin_amdgcn_mfma_f32_32x32x16_bf16(a, br, ar, 0, 0, 0);
            az = __builtin_amdgcn_mfma_f32_32x32x16_bf16(a, bz, az, 0, 0, 0);
            if (kc < 256) anx = __builtin_amdgcn_mfma_f32_32x32x16_bf16(a, bn, anx, 0, 0, 0);
            else          anh = __builtin_amdgcn_mfma_f32_32x32x16_bf16(a, bn, anh, 0, 0, 0);
        }
    }
    float rb = bih[cg] + bhh[cg];
    float zb = bih[256 + cg] + bhh[256 + cg];
    float bin = bih[512 + cg], bhn = bhh[512 + cg];
    #pragma unroll
    for (int r = 0; r < 16; ++r){
        int m = m0 + w * 32 + (r & 3) + 8 * (r >> 2) + 4 * half;
        if (m < N_DSTN){
            float h0v = H0[(size_t)m * 256 + cg];
            float rrg = 1.f / (1.f + __expf(-(ar[r] + rb)));
            float zz = 1.f / (1.f + __expf(-(az[r] + zb)));
            float nx = anx[r] + bin + rrg * (anh[r] + bhn);
            float tm = __expf(-2.f * fabsf(nx));
            float nn = (1.f - tm) / (1.f + tm);
            nn = (nx >= 0.f) ? nn : -nn;
            outH[(size_t)m * 256 + cg] = (1.f - zz) * nn + zz * h0v;
        }
    }
}

// ---- logits = h @ W_out + b_out ------------------------------------------
__global__ __launch_bounds__(256) void logits_kernel(
        const float* __restrict__ H, const float* __restrict__ Wout,
        const float* __restrict__ bout, float* __restrict__ outL){
    __shared__ float Hl[16 * 260];
    __shared__ float Wl[16 * 260];
    int tid = threadIdx.x;
    int m0 = blockIdx.x * 16;
    #pragma unroll
    for (int i = 0; i < 4; ++i){
        int ci = tid + i * 256;
        int row = ci >> 6;
        int c4 = (ci & 63) << 2;
        int gr = m0 + row; if (gr >= N_DSTN) gr = N_DSTN - 1;
        float4 v = *reinterpret_cast<const float4*>(H + (size_t)gr * 256 + c4);
        float* dp = Hl + row * 260 + c4;
        dp[0] = v.x; dp[1] = v.y; dp[2] = v.z; dp[3] = v.w;
    }
    #pragma unroll
    for (int i = 0; i < 16; ++i){
        int ci = tid + i * 256;
        int c = ci >> 4, j = ci & 15;
        Wl[j * 260 + c] = Wout[c * 16 + j];
    }
    __syncthreads();
    int row = tid >> 4, j = tid & 15;
    const float* hr = Hl + row * 260;
    const float* wr = Wl + j * 260;
    float acc = bout[j];
    #pragma unroll
    for (int c = 0; c < 256; c += 4){
        float4 hv = *reinterpret_cast<const float4*>(hr + c);
        float4 wv = *reinterpret_cast<const float4*>(wr + c);
        acc = fmaf(hv.x, wv.x, fmaf(hv.y, wv.y, fmaf(hv.z, wv.z, fmaf(hv.w, wv.w, acc))));
    }
    int m = m0 + row;
    if (m < N_DSTN) outL[m * 16 + j] = acc;
}

extern "C" void kernel_launch(void* const* d_in, const int* in_sizes, int n_in,
                              void* d_out, int out_size, void* d_ws, size_t ws_size,
                              hipStream_t stream){
    const float* feat_gt = (const float*)d_in[0];
    const float* feat_ag = (const float*)d_in[1];
    const float* h0      = (const float*)d_in[2];
    const int*   e_src   = (const int*)d_in[3];
    const int*   e_dst   = (const int*)d_in[4];
    const float* W_src   = (const float*)d_in[5];
    const float* b_src   = (const float*)d_in[6];
    const float* W_dst   = (const float*)d_in[7];
    const float* b_dst   = (const float*)d_in[8];
    const float* attn    = (const float*)d_in[9];
    const float* W_res   = (const float*)d_in[10];
    const float* b_res   = (const float*)d_in[11];
    const float* W_ih    = (const float*)d_in[12];
    const float* W_hh    = (const float*)d_in[13];
    const float* b_ih    = (const float*)d_in[14];
    const float* b_hh    = (const float*)d_in[15];
    const float* W_out   = (const float*)d_in[16];
    const float* b_out   = (const float*)d_in[17];

    float* outL = (float*)d_out;
    float* outH = outL + (size_t)N_DSTN * 16;

    char* ws = (char*)d_ws;
    size_t off = 0;
    auto alloc = [&](size_t bytes) -> void* {
        void* p = ws + off; off = (off + bytes + 255) & ~(size_t)255; return p;
    };
    unsigned short* fs   = (unsigned short*)alloc((size_t)N_SRCN * 256 * 2);
    unsigned short* fd   = (unsigned short*)alloc((size_t)N_DSTN * 256 * 2);
    unsigned short* res  = (unsigned short*)alloc((size_t)N_DSTN * 256 * 2);
    unsigned short* xb   = (unsigned short*)alloc((size_t)N_DSTN * 256 * 2);
    unsigned short* Wt2  = (unsigned short*)alloc(49152 * 2);
    unsigned short* Wf   = (unsigned short*)alloc(393216 * 2);
    int* deg    = (int*)alloc(N_DSTN * 4);
    int* ptr    = (int*)alloc(N_DSTN * 4);
    int* cursor = (int*)alloc(N_DSTN * 4);
    int* csr    = (int*)alloc((size_t)NE * 4);
    int* bsum   = (int*)alloc(256 * 4);
    int* boff   = (int*)alloc(256 * 4);

    hipMemsetAsync(deg, 0, N_DSTN * 4, stream);
    pack_kernel<<<1728, 256, 0, stream>>>(W_src, W_dst, W_res, W_ih, W_hh, Wt2, Wf);

    proj_kernel<<<dim3(4, 782, 3), 256, 0, stream>>>(feat_gt, feat_ag, Wt2,
                                                     b_src, b_dst, b_res, fs, fd, res);

    degree_kernel<<<3125, 256, 0, stream>>>(e_dst, deg);
    scan1_kernel<<<196, 256, 0, stream>>>(deg, bsum);
    scan2_kernel<<<1, 256, 0, stream>>>(bsum, boff);
    scan3_kernel<<<196, 256, 0, stream>>>(deg, boff, ptr, cursor);
    scatter_kernel<<<3125, 256, 0, stream>>>(e_src, e_dst, cursor, csr);
    aggregate_kernel<<<12500, 256, 0, stream>>>(fs, fd, res, attn, ptr, deg, csr, xb);

    gru_kernel<<<3136, 256, 0, stream>>>(xb, h0, Wf, b_ih, b_hh, outH);
    logits_kernel<<<3125, 256, 0, stream>>>(outH, W_out, b_out, outL);
}